// Round 2
// baseline (418.260 us; speedup 1.0000x reference)
//
#include <hip/hip_runtime.h>

// out[i,j] = (2*x[i,j] + 3) / (i + 1), x: 8192x8192 fp32.
// Memory-bound streaming: 512 MiB total traffic -> ~85 us at 6.3 TB/s.
// R2: 32 B/lane (2x float4 per thread) for 2x memory-level parallelism,
// nontemporal loads/stores to bypass L2 pollution (both streams are 256 MiB,
// 8x the 32 MiB aggregate L2 -- pure streaming, zero reuse).
// Each thread covers elements [8t, 8t+8); 8192 % 8 == 0 so both float4s are
// in the same row: row = (8t) >> 13.

typedef float v4f __attribute__((ext_vector_type(4)));

__global__ __launch_bounds__(256) void rowdiv_kernel(const v4f* __restrict__ x,
                                                     v4f* __restrict__ out) {
    const unsigned int t = blockIdx.x * blockDim.x + threadIdx.x;
    const unsigned int v = t * 2u;               // first float4 index
    const unsigned int row = v >> 11u;           // (v*4) >> 13
    const float inv = 1.0f / (float)(row + 1u);  // exact divide once, then mul

    v4f a0 = __builtin_nontemporal_load(x + v);
    v4f a1 = __builtin_nontemporal_load(x + v + 1);

    v4f r0 = (a0 * 2.0f + 3.0f) * inv;
    v4f r1 = (a1 * 2.0f + 3.0f) * inv;

    __builtin_nontemporal_store(r0, out + v);
    __builtin_nontemporal_store(r1, out + v + 1);
}

extern "C" void kernel_launch(void* const* d_in, const int* in_sizes, int n_in,
                              void* d_out, int out_size, void* d_ws, size_t ws_size,
                              hipStream_t stream) {
    const v4f* x = (const v4f*)d_in[0];
    v4f* out = (v4f*)d_out;
    // 8192*8192 = 67,108,864 elements = 16,777,216 float4s, 2 per thread
    const unsigned int n_threads = 8192u * 8192u / 8u; // 8,388,608
    const unsigned int block = 256;
    const unsigned int grid = n_threads / block;       // 32768
    rowdiv_kernel<<<grid, block, 0, stream>>>(x, out);
}